// Round 12
// baseline (959.351 us; speedup 1.0000x reference)
//
#include <hip/hip_runtime.h>
#include <math.h>

#define NN 12288
#define DD 128
#define EPSF 1e-7f
#define MAXNORM (1.0f - 1e-3f)
#define CSPLIT 16
#define CCOLS (NN / CSPLIT)      /* 768 columns per block */
#define CSTEPS (CCOLS / 128)     /* 6 steps of 128 columns */
#define SLABS (CSTEPS / 2)       /* 3 LDS slabs of 256 columns (64 KB) */

typedef __attribute__((ext_vector_type(8))) short short8_t;
typedef __attribute__((ext_vector_type(4))) float float4_t;
typedef unsigned short ushort_t;

__device__ __forceinline__ unsigned short f2bf(float f) {
    unsigned int u = __builtin_bit_cast(unsigned int, f);
    unsigned int r = u + 0x7FFFu + ((u >> 16) & 1u);
    return (unsigned short)(r >> 16);
}

// ---------------- Kernel 1: per-row prep ----------------
__global__ __launch_bounds__(128) void prep_kernel(
    const float* __restrict__ x, const float* __restrict__ a,
    ushort_t* __restrict__ xtb,
    float* __restrict__ wh1, float* __restrict__ wh2)
{
    const int r = blockIdx.x;
    const int t = threadIdx.x;
    const float xv = x[r * DD + t];
    const float a1 = a[t];
    const float a2 = a[DD + t];
    float s0 = xv * xv, s1 = xv * a1, s2 = xv * a2;
    #pragma unroll
    for (int o = 32; o > 0; o >>= 1) {
        s0 += __shfl_xor(s0, o);
        s1 += __shfl_xor(s1, o);
        s2 += __shfl_xor(s2, o);
    }
    __shared__ float red[6];
    const int w = t >> 6;
    if ((t & 63) == 0) { red[w * 3 + 0] = s0; red[w * 3 + 1] = s1; red[w * 3 + 2] = s2; }
    __syncthreads();
    const float sumsq = red[0] + red[3];
    const float d1    = red[1] + red[4];
    const float d2    = red[2] + red[5];
    const float nraw  = sqrtf(sumsq);
    const float nrm   = fminf(fmaxf(nraw, EPSF), 1.0f - EPSF);
    const float scale = atanhf(nrm) / nrm;
    xtb[(size_t)r * DD + t] = f2bf(xv * scale);
    if (t == 0) {
        wh1[r] = scale * d1;
        wh2[r] = scale * d2;
    }
}

// ---------------- Kernel 2: build xtB in MFMA-B-fragment-linear layout ----
// chunk C (32 j), dt: 1 KB block; element (lane, e) = xt[C*32+(lane>>4)*8+e][dt*16+(lane&15)]
__global__ __launch_bounds__(256) void swizzle_kernel(
    const ushort_t* __restrict__ xtb, ushort_t* __restrict__ xtB)
{
    __shared__ ushort_t raw[32 * 136];
    const int C = blockIdx.x;
    const int t = threadIdx.x;
    #pragma unroll
    for (int p = 0; p < 2; ++p) {
        const int idx = p * 256 + t;
        const int j = idx >> 4, cell = idx & 15;
        const uint4 v = *(const uint4*)(xtb + (size_t)(C * 32 + j) * DD + cell * 8);
        *(uint4*)&raw[j * 136 + cell * 8] = v;
    }
    __syncthreads();
    #pragma unroll
    for (int p = 0; p < 2; ++p) {
        const int oc = p * 256 + t;       // 0..511 = dt*64 + lane
        const int dt = oc >> 6;
        const int l6 = oc & 63;
        const int l15 = l6 & 15, q = l6 >> 4;
        short8_t v;
        #pragma unroll
        for (int e = 0; e < 8; ++e)
            v[e] = (short)raw[(q * 8 + e) * 136 + dt * 16 + l15];
        *(short8_t*)(xtB + (size_t)C * 4096 + oc * 8) = v;
    }
}

// ---------------- Kernel 3: flash MFMA attention, 4 waves/SIMD --------------
// r11 falsified the memory theory: attn ran ~200 us with the 604 MB adj
// stream AND ~210 us with a 19 MB L3-resident bitmask -> the bound is the
// exposed per-kc dependency chain (ds_read ~120cyc -> exp -> f2bf -> MFMA)
// at 2 waves/SIMD. This round doubles TLP without touching the verified
// inner loop: 512-thread blocks (8 waves) share ONE 64 KB slab; 128 rows x
// 768 cols per block (CSPLIT=16); LDS 67 KB -> 2 blocks/CU = 4 waves/SIMD
// (__launch_bounds__(512,4), VGPR cap 128, live set ~100). Grid 96x16 =
// 1536 = 3.0 exact rounds. Adjacency: direct adj stream + u32 bitmask
// compress (r10-verbatim pipeline).
__global__ __launch_bounds__(512, 4) void attn_kernel(
    const int* __restrict__ adj,
    const ushort_t* __restrict__ xtB,
    const float* __restrict__ wh1, const float* __restrict__ wh2,
    float* __restrict__ pout, float* __restrict__ plsum)
{
    __shared__ __align__(16) ushort_t B_lds[256 * DD];   // 64 KB
    __shared__ __align__(16) float wh2_lds[CCOLS];       //  3 KB

    const int t = threadIdx.x;
    const int w = t >> 6, lane = t & 63;
    const int l15 = lane & 15, quad = lane >> 4;
    const int cy = blockIdx.y;
    const int jcol0 = cy * CCOLS;
    const int rowbase = blockIdx.x * 128 + w * 16;   // wave's 16 rows

    if (t < CCOLS) wh2_lds[t] = wh2[jcol0 + t];
    if (t < CCOLS - 512) wh2_lds[512 + t] = wh2[jcol0 + 512 + t];
    const float wh1i = wh1[rowbase + l15];

    const int* adj_lane = adj + (size_t)(rowbase + l15) * NN + jcol0 + quad * 8;
    // slab sl = 64 KB contiguous: Bsrc + sl*4096 uint4
    const uint4* Bsrc = (const uint4*)(xtB + (size_t)(jcol0 >> 5) * 4096);

    float4_t acc[8];
    #pragma unroll
    for (int dt = 0; dt < 8; ++dt) acc[dt] = (float4_t)0.0f;
    float lsum = 0.0f;

    int4 R[8];             // single adj load buffer (static indexing)
    unsigned mCur;         // current step's 32-col bitmask (bit kc*8+e)

    auto adj_load = [&](int st) {
        const int* bp = adj_lane + st * 128;
        #pragma unroll
        for (int kc = 0; kc < 4; ++kc) {
            R[kc * 2 + 0] = *(const int4*)(bp + kc * 32);
            R[kc * 2 + 1] = *(const int4*)(bp + kc * 32 + 4);
        }
    };

    auto compress = [&]() -> unsigned {
        unsigned m = 0;
        #pragma unroll
        for (int kc = 0; kc < 4; ++kc) {
            const int4 a0 = R[kc * 2 + 0], a1 = R[kc * 2 + 1];
            m |= (a0.x > 0 ? 1u : 0u) << (kc * 8 + 0);
            m |= (a0.y > 0 ? 1u : 0u) << (kc * 8 + 1);
            m |= (a0.z > 0 ? 1u : 0u) << (kc * 8 + 2);
            m |= (a0.w > 0 ? 1u : 0u) << (kc * 8 + 3);
            m |= (a1.x > 0 ? 1u : 0u) << (kc * 8 + 4);
            m |= (a1.y > 0 ? 1u : 0u) << (kc * 8 + 5);
            m |= (a1.z > 0 ? 1u : 0u) << (kc * 8 + 6);
            m |= (a1.w > 0 ? 1u : 0u) << (kc * 8 + 7);
        }
        return m;
    };

    // stage one 256-col slab (64 KB) via async global->LDS DMA: 8 waves x
    // 8 insts x 1 KB = 64 KB, linear (dest = wave-uniform base + lane*16).
    auto stage = [&](int sl) {
        const uint4* gp = Bsrc + (size_t)sl * 4096 + (size_t)w * 512 + lane;
        char* lb = (char*)B_lds + (size_t)w * 8192;
        #pragma unroll
        for (int m = 0; m < 8; ++m) {
            __builtin_amdgcn_global_load_lds(
                (const __attribute__((address_space(1))) unsigned int*)(gp + m * 64),
                (__attribute__((address_space(3))) unsigned int*)(lb + (size_t)m * 1024),
                16, 0, 0);
        }
    };

    auto compute = [&](int st, int par, unsigned mask) {
        #pragma unroll
        for (int kc = 0; kc < 4; ++kc) {
            const unsigned wq = (mask >> (kc * 8)) & 0xFFu;
            const int wbase = st * 128 + kc * 32 + quad * 8;
            const float4 Wa = *(const float4*)&wh2_lds[wbase];
            const float4 Wb = *(const float4*)&wh2_lds[wbase + 4];
            const float u0 = wh1i + Wa.x, u1 = wh1i + Wa.y;
            const float u2 = wh1i + Wa.z, u3 = wh1i + Wa.w;
            const float u4 = wh1i + Wb.x, u5 = wh1i + Wb.y;
            const float u6 = wh1i + Wb.z, u7 = wh1i + Wb.w;
            const float p0 = (wq & 1u)   ? __expf(fmaxf(u0, 0.2f * u0)) : 0.0f;
            const float p1 = (wq & 2u)   ? __expf(fmaxf(u1, 0.2f * u1)) : 0.0f;
            const float p2 = (wq & 4u)   ? __expf(fmaxf(u2, 0.2f * u2)) : 0.0f;
            const float p3 = (wq & 8u)   ? __expf(fmaxf(u3, 0.2f * u3)) : 0.0f;
            const float p4 = (wq & 16u)  ? __expf(fmaxf(u4, 0.2f * u4)) : 0.0f;
            const float p5 = (wq & 32u)  ? __expf(fmaxf(u5, 0.2f * u5)) : 0.0f;
            const float p6 = (wq & 64u)  ? __expf(fmaxf(u6, 0.2f * u6)) : 0.0f;
            const float p7 = (wq & 128u) ? __expf(fmaxf(u7, 0.2f * u7)) : 0.0f;
            lsum += ((p0 + p1) + (p2 + p3)) + ((p4 + p5) + (p6 + p7));
            short8_t af;
            af[0] = (short)f2bf(p0); af[1] = (short)f2bf(p1);
            af[2] = (short)f2bf(p2); af[3] = (short)f2bf(p3);
            af[4] = (short)f2bf(p4); af[5] = (short)f2bf(p5);
            af[6] = (short)f2bf(p6); af[7] = (short)f2bf(p7);
            // B within current slab: 32-col chunk par*4 + kc (static)
            const ushort_t* Bp = B_lds + (par * 4 + kc) * 4096 + lane * 8;
            #pragma unroll
            for (int dt = 0; dt < 8; ++dt) {
                const short8_t Bf = *(const short8_t*)(Bp + dt * 512);
                acc[dt] = __builtin_amdgcn_mfma_f32_16x16x32_bf16(af, Bf, acc[dt], 0, 0, 0);
            }
        }
    };

    // ---- prologue: mask(0) ready, loads(1) in flight ----
    adj_load(0);
    mCur = compress();
    adj_load(1);

    // ---- slab loop: runtime sl, 2 parity-static steps inside ----
    #pragma unroll 1
    for (int sl = 0; sl < SLABS; ++sl) {
        const int st0 = sl * 2;
        __syncthreads();            // all waves done reading previous slab
        stage(sl);                  // async DMA this slab's B
        __syncthreads();            // DMA drained -> slab visible
        // step A (parity 0): consume mask(st0); R holds data(st0+1)
        compute(st0 + 0, 0, mCur);
        mCur = compress();                        // waits loads(st0+1)
        if (st0 + 2 < CSTEPS) adj_load(st0 + 2);
        // step B (parity 1): consume mask(st0+1); R holds data(st0+2)
        compute(st0 + 1, 1, mCur);
        if (st0 + 2 < CSTEPS) {
            mCur = compress();                    // waits loads(st0+2)
            if (st0 + 3 < CSTEPS) adj_load(st0 + 3);
        }
    }

    // ---- epilogue: one partial per column-slice ----
    float v = lsum;
    v += __shfl_xor(v, 16);
    v += __shfl_xor(v, 32);
    if (quad == 0) plsum[(size_t)cy * NN + rowbase + l15] = v;
    #pragma unroll
    for (int dt = 0; dt < 8; ++dt)
        #pragma unroll
        for (int reg = 0; reg < 4; ++reg)
            pout[((size_t)cy * NN + rowbase + quad * 4 + reg) * DD + dt * 16 + l15]
                = acc[dt][reg];
}

// ---------------- Kernel 4: combine partials + normalize + expmap0 + proj ----
__global__ __launch_bounds__(128) void reduce_kernel(
    const float* __restrict__ pout, const float* __restrict__ plsum,
    float* __restrict__ out)
{
    const int i = blockIdx.x;
    const int t = threadIdx.x;
    float v = 0.0f;
    #pragma unroll
    for (int s = 0; s < CSPLIT; ++s) v += pout[((size_t)s * NN + i) * DD + t];
    float ls = 0.0f;
    #pragma unroll
    for (int s = 0; s < CSPLIT; ++s) ls += plsum[(size_t)s * NN + i];
    v /= ls;
    float ss = v * v;
    #pragma unroll
    for (int o = 1; o < 64; o <<= 1) ss += __shfl_xor(ss, o);
    __shared__ float r2[2];
    if ((t & 63) == 0) r2[t >> 6] = ss;
    __syncthreads();
    const float total = r2[0] + r2[1];
    const float nraw = sqrtf(total);
    const float nv   = fmaxf(nraw, EPSF);
    const float th   = tanhf(nv);
    const float ysc  = th / nv;
    const float nyr  = ysc * nraw;
    const float ny   = fmaxf(nyr, EPSF);
    const float psc  = (ny > MAXNORM) ? (MAXNORM / ny) : 1.0f;
    const float os   = ysc * psc;
    out[(size_t)i * DD + t] = v * os;
}

extern "C" void kernel_launch(void* const* d_in, const int* in_sizes, int n_in,
                              void* d_out, int out_size, void* d_ws, size_t ws_size,
                              hipStream_t stream) {
    const float* x   = (const float*)d_in[0];
    const int*   adj = (const int*)d_in[1];
    const float* a   = (const float*)d_in[2];
    float* out = (float*)d_out;

    // ---- workspace layout (~110 MB; ws is ~2.4 GB) ----
    char* ws = (char*)d_ws;
    ushort_t* xtb = (ushort_t*)ws;  ws += (size_t)NN * DD * sizeof(ushort_t);
    ushort_t* xtB = (ushort_t*)ws;  ws += (size_t)NN * DD * sizeof(ushort_t);
    float* wh1 = (float*)ws;        ws += NN * sizeof(float);
    float* wh2 = (float*)ws;        ws += NN * sizeof(float);
    float* plsum = (float*)ws;      ws += (size_t)CSPLIT * NN * sizeof(float);
    float* pout  = (float*)ws;

    prep_kernel<<<NN, 128, 0, stream>>>(x, a, xtb, wh1, wh2);
    swizzle_kernel<<<NN / 32, 256, 0, stream>>>(xtb, xtB);
    attn_kernel<<<dim3(NN / 128, CSPLIT), 512, 0, stream>>>(
        adj, xtB, wh1, wh2, pout, plsum);
    reduce_kernel<<<NN, 128, 0, stream>>>(pout, plsum, out);
}

// Round 13
// 837.217 us; speedup vs baseline: 1.1459x; 1.1459x over previous
//
#include <hip/hip_runtime.h>
#include <math.h>

#define NN 12288
#define DD 128
#define EPSF 1e-7f
#define MAXNORM (1.0f - 1e-3f)
#define CSPLIT 8
#define CCOLS (NN / CSPLIT)      /* 1536 columns per block */
#define CSTEPS (CCOLS / 128)     /* 12 steps of 128 columns */
#define SLABS (CSTEPS / 2)       /* 6 LDS slabs of 256 columns (64 KB) */

typedef __attribute__((ext_vector_type(8))) short short8_t;
typedef __attribute__((ext_vector_type(4))) float float4_t;
typedef unsigned short ushort_t;

__device__ __forceinline__ unsigned short f2bf(float f) {
    unsigned int u = __builtin_bit_cast(unsigned int, f);
    unsigned int r = u + 0x7FFFu + ((u >> 16) & 1u);
    return (unsigned short)(r >> 16);
}

// ---------------- Kernel 1: per-row prep ----------------
__global__ __launch_bounds__(128) void prep_kernel(
    const float* __restrict__ x, const float* __restrict__ a,
    ushort_t* __restrict__ xtb,
    float* __restrict__ wh1, float* __restrict__ wh2)
{
    const int r = blockIdx.x;
    const int t = threadIdx.x;
    const float xv = x[r * DD + t];
    const float a1 = a[t];
    const float a2 = a[DD + t];
    float s0 = xv * xv, s1 = xv * a1, s2 = xv * a2;
    #pragma unroll
    for (int o = 32; o > 0; o >>= 1) {
        s0 += __shfl_xor(s0, o);
        s1 += __shfl_xor(s1, o);
        s2 += __shfl_xor(s2, o);
    }
    __shared__ float red[6];
    const int w = t >> 6;
    if ((t & 63) == 0) { red[w * 3 + 0] = s0; red[w * 3 + 1] = s1; red[w * 3 + 2] = s2; }
    __syncthreads();
    const float sumsq = red[0] + red[3];
    const float d1    = red[1] + red[4];
    const float d2    = red[2] + red[5];
    const float nraw  = sqrtf(sumsq);
    const float nrm   = fminf(fmaxf(nraw, EPSF), 1.0f - EPSF);
    const float scale = atanhf(nrm) / nrm;
    xtb[(size_t)r * DD + t] = f2bf(xv * scale);
    if (t == 0) {
        wh1[r] = scale * d1;
        wh2[r] = scale * d2;
    }
}

// ---------------- Kernel 2: build xtB in MFMA-B-fragment-linear layout ----
// chunk C (32 j), dt: 1 KB block; element (lane, e) = xt[C*32+(lane>>4)*8+e][dt*16+(lane&15)]
__global__ __launch_bounds__(256) void swizzle_kernel(
    const ushort_t* __restrict__ xtb, ushort_t* __restrict__ xtB)
{
    __shared__ ushort_t raw[32 * 136];
    const int C = blockIdx.x;
    const int t = threadIdx.x;
    #pragma unroll
    for (int p = 0; p < 2; ++p) {
        const int idx = p * 256 + t;
        const int j = idx >> 4, cell = idx & 15;
        const uint4 v = *(const uint4*)(xtb + (size_t)(C * 32 + j) * DD + cell * 8);
        *(uint4*)&raw[j * 136 + cell * 8] = v;
    }
    __syncthreads();
    #pragma unroll
    for (int p = 0; p < 2; ++p) {
        const int oc = p * 256 + t;       // 0..511 = dt*64 + lane
        const int dt = oc >> 6;
        const int l6 = oc & 63;
        const int l15 = l6 & 15, q = l6 >> 4;
        short8_t v;
        #pragma unroll
        for (int e = 0; e < 8; ++e)
            v[e] = (short)raw[(q * 8 + e) * 136 + dt * 16 + l15];
        *(short8_t*)(xtB + (size_t)C * 4096 + oc * 8) = v;
    }
}

// ---------------- Kernel 3: flash MFMA attention, factored-exp -------------
// r10 shape verbatim (CSPLIT=8, 256 thr, 64 KB slab, 2 blk/CU, adj compress
// pipeline). NEW: the per-element exp chain (add->max->__expf->f2bf) is
// ELIMINATED via the identity exp(leakyrelu(wh1+wh2)) =
//   u>0 ? e^wh1 * e^wh2 : e^{.2wh1} * e^{.2wh2}.
// Per block we precompute bf16 e2[j]=e^wh2_j, e25[j]=e^{.2wh2_j} in LDS
// (12288 exps total replace 151M). Inner loop per element: adj-bit AND sign
// test (wh2_j > -wh1_i) -> cndmask-select of pre-stored bf16. Row factors
// c1,c15 applied AFTER the matmul via two accumulator sets; row sums come
// from two extra MFMAs against an all-ones B-fragment (18 MFMA/kc, matrix
// pipe was ~5% busy). acc 72 VGPR, budget 256 at (256,2). LDS 76 KB.
__global__ __launch_bounds__(256, 2) void attn_kernel(
    const int* __restrict__ adj,
    const ushort_t* __restrict__ xtB,
    const float* __restrict__ wh1, const float* __restrict__ wh2,
    float* __restrict__ pout, float* __restrict__ plsum)
{
    __shared__ __align__(16) ushort_t B_lds[256 * DD];   // 64 KB
    __shared__ __align__(16) float wh2_lds[CCOLS];       //  6 KB (sign test)
    __shared__ __align__(16) ushort_t e2_lds[CCOLS];     //  3 KB  e^wh2
    __shared__ __align__(16) ushort_t e25_lds[CCOLS];    //  3 KB  e^{.2wh2}

    const int t = threadIdx.x;
    const int w = t >> 6, lane = t & 63;
    const int l15 = lane & 15, quad = lane >> 4;
    const int cy = blockIdx.y;
    const int jcol0 = cy * CCOLS;
    const int rowbase = blockIdx.x * 64 + w * 16;    // wave's 16 rows

    #pragma unroll
    for (int m = 0; m < CCOLS / 256; ++m) {
        const float v = wh2[jcol0 + m * 256 + t];
        wh2_lds[m * 256 + t] = v;
        e2_lds[m * 256 + t]  = f2bf(__expf(v));
        e25_lds[m * 256 + t] = f2bf(__expf(0.2f * v));
    }
    const float wh1i = wh1[rowbase + l15];
    const float T = -wh1i;                  // sign test: u>0 <=> wh2_j > T

    // row factors for the C-layout rows this thread owns (quad*4+reg)
    float c1r[4], c15r[4];
    #pragma unroll
    for (int reg = 0; reg < 4; ++reg) {
        const float wr = wh1[rowbase + quad * 4 + reg];
        c1r[reg]  = __expf(wr);
        c15r[reg] = __expf(0.2f * wr);
    }

    const int* adj_lane = adj + (size_t)(rowbase + l15) * NN + jcol0 + quad * 8;
    // slab sl = 64 KB contiguous: Bsrc + sl*4096 uint4
    const uint4* Bsrc = (const uint4*)(xtB + (size_t)(jcol0 >> 5) * 4096);

    float4_t accP[8], accN[8], sP, sN;
    #pragma unroll
    for (int dt = 0; dt < 8; ++dt) { accP[dt] = (float4_t)0.0f; accN[dt] = (float4_t)0.0f; }
    sP = (float4_t)0.0f; sN = (float4_t)0.0f;

    short8_t onesf;        // bf16 1.0 fragment for row-sum MFMA
    #pragma unroll
    for (int e = 0; e < 8; ++e) onesf[e] = (short)0x3F80;

    int4 R[8];             // single adj load buffer (static indexing)
    unsigned mCur;         // current step's 32-col bitmask (bit kc*8+e)

    auto adj_load = [&](int st) {
        const int* bp = adj_lane + st * 128;
        #pragma unroll
        for (int kc = 0; kc < 4; ++kc) {
            R[kc * 2 + 0] = *(const int4*)(bp + kc * 32);
            R[kc * 2 + 1] = *(const int4*)(bp + kc * 32 + 4);
        }
    };

    auto compress = [&]() -> unsigned {
        unsigned m = 0;
        #pragma unroll
        for (int kc = 0; kc < 4; ++kc) {
            const int4 a0 = R[kc * 2 + 0], a1 = R[kc * 2 + 1];
            m |= (a0.x > 0 ? 1u : 0u) << (kc * 8 + 0);
            m |= (a0.y > 0 ? 1u : 0u) << (kc * 8 + 1);
            m |= (a0.z > 0 ? 1u : 0u) << (kc * 8 + 2);
            m |= (a0.w > 0 ? 1u : 0u) << (kc * 8 + 3);
            m |= (a1.x > 0 ? 1u : 0u) << (kc * 8 + 4);
            m |= (a1.y > 0 ? 1u : 0u) << (kc * 8 + 5);
            m |= (a1.z > 0 ? 1u : 0u) << (kc * 8 + 6);
            m |= (a1.w > 0 ? 1u : 0u) << (kc * 8 + 7);
        }
        return m;
    };

    // stage one 256-col slab (64 KB) via async global->LDS DMA (no VGPRs)
    auto stage = [&](int sl) {
        const uint4* gp = Bsrc + (size_t)sl * 4096 + (size_t)w * 64 + lane;
        char* lb = (char*)B_lds + (size_t)w * 64 * 16;
        #pragma unroll
        for (int m = 0; m < 16; ++m) {
            __builtin_amdgcn_global_load_lds(
                (const __attribute__((address_space(1))) unsigned int*)(gp + m * 256),
                (__attribute__((address_space(3))) unsigned int*)(lb + (size_t)m * 256 * 16),
                16, 0, 0);
        }
    };

    auto compute = [&](int st, int par, unsigned mask) {
        #pragma unroll
        for (int kc = 0; kc < 4; ++kc) {
            const unsigned wq = (mask >> (kc * 8)) & 0xFFu;
            const int wbase = st * 128 + kc * 32 + quad * 8;
            const float4 Wa = *(const float4*)&wh2_lds[wbase];
            const float4 Wb = *(const float4*)&wh2_lds[wbase + 4];
            const short8_t e2v  = *(const short8_t*)&e2_lds[wbase];
            const short8_t e25v = *(const short8_t*)&e25_lds[wbase];
            short8_t afp, afn;
            afp[0] = ((wq &   1u) && (Wa.x > T)) ? e2v[0] : (short)0;
            afn[0] = ((wq &   1u) && !(Wa.x > T)) ? e25v[0] : (short)0;
            afp[1] = ((wq &   2u) && (Wa.y > T)) ? e2v[1] : (short)0;
            afn[1] = ((wq &   2u) && !(Wa.y > T)) ? e25v[1] : (short)0;
            afp[2] = ((wq &   4u) && (Wa.z > T)) ? e2v[2] : (short)0;
            afn[2] = ((wq &   4u) && !(Wa.z > T)) ? e25v[2] : (short)0;
            afp[3] = ((wq &   8u) && (Wa.w > T)) ? e2v[3] : (short)0;
            afn[3] = ((wq &   8u) && !(Wa.w > T)) ? e25v[3] : (short)0;
            afp[4] = ((wq &  16u) && (Wb.x > T)) ? e2v[4] : (short)0;
            afn[4] = ((wq &  16u) && !(Wb.x > T)) ? e25v[4] : (short)0;
            afp[5] = ((wq &  32u) && (Wb.y > T)) ? e2v[5] : (short)0;
            afn[5] = ((wq &  32u) && !(Wb.y > T)) ? e25v[5] : (short)0;
            afp[6] = ((wq &  64u) && (Wb.z > T)) ? e2v[6] : (short)0;
            afn[6] = ((wq &  64u) && !(Wb.z > T)) ? e25v[6] : (short)0;
            afp[7] = ((wq & 128u) && (Wb.w > T)) ? e2v[7] : (short)0;
            afn[7] = ((wq & 128u) && !(Wb.w > T)) ? e25v[7] : (short)0;
            // B within current slab: 32-col chunk par*4 + kc (static)
            const ushort_t* Bp = B_lds + (par * 4 + kc) * 4096 + lane * 8;
            #pragma unroll
            for (int dt = 0; dt < 8; ++dt) {
                const short8_t Bf = *(const short8_t*)(Bp + dt * 512);
                accP[dt] = __builtin_amdgcn_mfma_f32_16x16x32_bf16(afp, Bf, accP[dt], 0, 0, 0);
                accN[dt] = __builtin_amdgcn_mfma_f32_16x16x32_bf16(afn, Bf, accN[dt], 0, 0, 0);
            }
            sP = __builtin_amdgcn_mfma_f32_16x16x32_bf16(afp, onesf, sP, 0, 0, 0);
            sN = __builtin_amdgcn_mfma_f32_16x16x32_bf16(afn, onesf, sN, 0, 0, 0);
        }
    };

    // ---- prologue: mask(0) ready, loads(1) in flight ----
    adj_load(0);
    mCur = compress();
    adj_load(1);

    // ---- slab loop: runtime sl, 2 parity-static steps inside ----
    #pragma unroll 1
    for (int sl = 0; sl < SLABS; ++sl) {
        const int st0 = sl * 2;
        __syncthreads();            // all waves done reading previous slab
        stage(sl);                  // async DMA this slab's B
        __syncthreads();            // DMA drained -> slab visible
        // step A (parity 0): consume mask(st0); R holds data(st0+1)
        compute(st0 + 0, 0, mCur);
        mCur = compress();                        // waits loads(st0+1)
        if (st0 + 2 < CSTEPS) adj_load(st0 + 2);
        // step B (parity 1): consume mask(st0+1); R holds data(st0+2)
        compute(st0 + 1, 1, mCur);
        if (st0 + 2 < CSTEPS) {
            mCur = compress();                    // waits loads(st0+2)
            if (st0 + 3 < CSTEPS) adj_load(st0 + 3);
        }
    }

    // ---- epilogue: apply row factors; one partial per column-slice ----
    #pragma unroll
    for (int reg = 0; reg < 4; ++reg) {
        const float ls = c1r[reg] * sP[reg] + c15r[reg] * sN[reg];
        if (l15 == 0)
            plsum[(size_t)cy * NN + rowbase + quad * 4 + reg] = ls;
    }
    #pragma unroll
    for (int dt = 0; dt < 8; ++dt)
        #pragma unroll
        for (int reg = 0; reg < 4; ++reg)
            pout[((size_t)cy * NN + rowbase + quad * 4 + reg) * DD + dt * 16 + l15]
                = c1r[reg] * accP[dt][reg] + c15r[reg] * accN[dt][reg];
}

// ---------------- Kernel 4: combine partials + normalize + expmap0 + proj ----
__global__ __launch_bounds__(128) void reduce_kernel(
    const float* __restrict__ pout, const float* __restrict__ plsum,
    float* __restrict__ out)
{
    const int i = blockIdx.x;
    const int t = threadIdx.x;
    float v = 0.0f;
    #pragma unroll
    for (int s = 0; s < CSPLIT; ++s) v += pout[((size_t)s * NN + i) * DD + t];
    float ls = 0.0f;
    #pragma unroll
    for (int s = 0; s < CSPLIT; ++s) ls += plsum[(size_t)s * NN + i];
    v /= ls;
    float ss = v * v;
    #pragma unroll
    for (int o = 1; o < 64; o <<= 1) ss += __shfl_xor(ss, o);
    __shared__ float r2[2];
    if ((t & 63) == 0) r2[t >> 6] = ss;
    __syncthreads();
    const float total = r2[0] + r2[1];
    const float nraw = sqrtf(total);
    const float nv   = fmaxf(nraw, EPSF);
    const float th   = tanhf(nv);
    const float ysc  = th / nv;
    const float nyr  = ysc * nraw;
    const float ny   = fmaxf(nyr, EPSF);
    const float psc  = (ny > MAXNORM) ? (MAXNORM / ny) : 1.0f;
    const float os   = ysc * psc;
    out[(size_t)i * DD + t] = v * os;
}

extern "C" void kernel_launch(void* const* d_in, const int* in_sizes, int n_in,
                              void* d_out, int out_size, void* d_ws, size_t ws_size,
                              hipStream_t stream) {
    const float* x   = (const float*)d_in[0];
    const int*   adj = (const int*)d_in[1];
    const float* a   = (const float*)d_in[2];
    float* out = (float*)d_out;

    // ---- workspace layout (~57 MB; ws is ~2.4 GB) ----
    char* ws = (char*)d_ws;
    ushort_t* xtb = (ushort_t*)ws;  ws += (size_t)NN * DD * sizeof(ushort_t);
    ushort_t* xtB = (ushort_t*)ws;  ws += (size_t)NN * DD * sizeof(ushort_t);
    float* wh1 = (float*)ws;        ws += NN * sizeof(float);
    float* wh2 = (float*)ws;        ws += NN * sizeof(float);
    float* plsum = (float*)ws;      ws += (size_t)CSPLIT * NN * sizeof(float);
    float* pout  = (float*)ws;

    prep_kernel<<<NN, 128, 0, stream>>>(x, a, xtb, wh1, wh2);
    swizzle_kernel<<<NN / 32, 256, 0, stream>>>(xtb, xtB);
    attn_kernel<<<dim3(NN / 64, CSPLIT), 256, 0, stream>>>(
        adj, xtB, wh1, wh2, pout, plsum);
    reduce_kernel<<<NN, 128, 0, stream>>>(pout, plsum, out);
}